// Round 10
// baseline (104.133 us; speedup 1.0000x reference)
//
#include <hip/hip_runtime.h>
#include <hip/hip_cooperative_groups.h>

namespace cg = cooperative_groups;

#define B_ 8
#define C_ 19
#define H_ 512
#define W_ 512
#define HW_ (H_*W_)
#define N_ (B_*HW_)
#define HW4 (HW_/4)          /* 65536 float4 per channel-plane */
#define N4 (N_/4)            /* 524288 */
#define CH4 (C_*HW4)
#define K_RANK 100000
#define NBINS 2048
#define MAIN_BLOCKS (N4/512) /* 1024: 8 pixels (2 float4) per thread */
#define SEL_BLOCKS 512

struct SelState { unsigned prefix; unsigned krem; float threshold; };

// ---------------- main: online-softmax CE, 8 pixels/thread (2 independent groups) ------
// CACHEABLE float4 loads: rounds 0-4 measured FETCH_SIZE 155.7MB vs 318.8MB read demand,
// i.e. the 256MB Infinity Cache serves ~half the input stream across timed replays.
// The round-6 nt loads forfeited that (full 318.8MB from HBM each replay). This round is
// the clean A/B vs round 8 (identical structure, only cache policy differs).
__global__ __launch_bounds__(256, 4) void main_kernel(const float4* __restrict__ logits,
                                                      const float4* __restrict__ target,
                                                      float4* __restrict__ pred,
                                                      float4* __restrict__ lossv,
                                                      double* __restrict__ spec) {
    int t  = threadIdx.x;
    int n4 = blockIdx.x * 512 + t;                 // group A; group B = n4 + 256
    int b   = n4 >> 16;                            // block fully inside one batch b
    int hw4 = n4 & (HW4 - 1);
    size_t base = (size_t)b * (size_t)CH4 + (size_t)hw4;
    const float4* lp = logits + base;
    const float4* tp = target + base;

    float mA[4] = {-3.4e38f,-3.4e38f,-3.4e38f,-3.4e38f};
    float mB[4] = {-3.4e38f,-3.4e38f,-3.4e38f,-3.4e38f};
    float sA[4] = {0,0,0,0}, sB[4] = {0,0,0,0};
    float tsA[4] = {0,0,0,0}, tsB[4] = {0,0,0,0};
    float tlA[4] = {0,0,0,0}, tlB[4] = {0,0,0,0};

#pragma unroll
    for (int c = 0; c < C_; ++c) {
        float4 la = lp[(size_t)c * HW4];
        float4 lb = lp[(size_t)c * HW4 + 256];
        float4 ta = tp[(size_t)c * HW4];
        float4 tb = tp[(size_t)c * HW4 + 256];
        float lav[4] = { la.x, la.y, la.z, la.w };
        float lbv[4] = { lb.x, lb.y, lb.z, lb.w };
        float tav[4] = { ta.x, ta.y, ta.z, ta.w };
        float tbv[4] = { tb.x, tb.y, tb.z, tb.w };
#pragma unroll
        for (int j = 0; j < 4; ++j) {
            float na = fmaxf(mA[j], lav[j]);
            sA[j] = fmaf(sA[j], __expf(mA[j] - na), __expf(lav[j] - na)); mA[j] = na;
            tsA[j] += tav[j];
            tlA[j] = fmaf(tav[j], lav[j], tlA[j]);
            float nb = fmaxf(mB[j], lbv[j]);
            sB[j] = fmaf(sB[j], __expf(mB[j] - nb), __expf(lbv[j] - nb)); mB[j] = nb;
            tsB[j] += tbv[j];
            tlB[j] = fmaf(tbv[j], lbv[j], tlB[j]);
        }
    }

    float loA[4], prA[4], loB[4], prB[4];
#pragma unroll
    for (int j = 0; j < 4; ++j) {
        loA[j] = tsA[j] * (mA[j] + __logf(sA[j])) - tlA[j];
        prA[j] = __expf(tlA[j] - mA[j]) / sA[j];
        loB[j] = tsB[j] * (mB[j] + __logf(sB[j])) - tlB[j];
        prB[j] = __expf(tlB[j] - mB[j]) / sB[j];
    }
    lossv[n4]       = make_float4(loA[0], loA[1], loA[2], loA[3]);
    pred[n4]        = make_float4(prA[0], prA[1], prA[2], prA[3]);
    lossv[n4 + 256] = make_float4(loB[0], loB[1], loB[2], loB[3]);
    pred[n4 + 256]  = make_float4(prB[0], prB[1], prB[2], prB[3]);

    // speculative thr == 0.7 masked partials (exact when kth < 0.7)
    double sl = 0.0, sm = 0.0;
#pragma unroll
    for (int j = 0; j < 4; ++j) {
        if (prA[j] < 0.7f) { sl += (double)loA[j]; sm += 1.0; }
        if (prB[j] < 0.7f) { sl += (double)loB[j]; sm += 1.0; }
    }
    __shared__ double sd1[256], sd2[256];
    sd1[t] = sl; sd2[t] = sm;
    __syncthreads();
    for (int off = 128; off > 0; off >>= 1) {
        if (t < off) { sd1[t] += sd1[t + off]; sd2[t] += sd2[t + off]; }
        __syncthreads();
    }
    if (t == 0) { spec[2 * blockIdx.x] = sd1[0]; spec[2 * blockIdx.x + 1] = sd2[0]; }
}

// ---------------- radix-select helpers (used only on the fallback path) ----------------
template <int PASS>
__device__ __forceinline__ void hist_pass(unsigned* lh, const float4* __restrict__ pred,
                                          unsigned* __restrict__ gh, unsigned prefix) {
    int t = threadIdx.x;
    for (int i = t; i < NBINS; i += 256) lh[i] = 0u;
    __syncthreads();
    int stride = gridDim.x * 256;
    for (int n = blockIdx.x * 256 + t; n < N4; n += stride) {
        float4 p = pred[n];
        unsigned u[4] = { __float_as_uint(p.x), __float_as_uint(p.y),
                          __float_as_uint(p.z), __float_as_uint(p.w) };
#pragma unroll
        for (int j = 0; j < 4; ++j) {
            unsigned v = u[j];
            if (PASS == 0)      atomicAdd(&lh[v >> 21], 1u);
            else if (PASS == 1) { if ((v & 0xFFE00000u) == prefix) atomicAdd(&lh[(v >> 10) & 0x7FFu], 1u); }
            else                { if ((v & 0xFFFFFC00u) == prefix) atomicAdd(&lh[v & 0x3FFu], 1u); }
        }
    }
    __syncthreads();
    for (int i = t; i < NBINS; i += 256) { unsigned v = lh[i]; if (v) atomicAdd(&gh[i], v); }
}

template <int PASS>
__device__ __forceinline__ void scan_pass(unsigned* ssum, const unsigned* __restrict__ gh,
                                          SelState* st) {
    int t = threadIdx.x;
    unsigned k = st->krem;
    unsigned local[8];
    unsigned lsum = 0;
#pragma unroll
    for (int i = 0; i < 8; ++i) { local[i] = gh[t * 8 + i]; lsum += local[i]; }
    ssum[t] = lsum;
    __syncthreads();
    unsigned val = lsum;
    for (int off = 1; off < 256; off <<= 1) {   // Hillis-Steele inclusive scan
        unsigned other = (t >= off) ? ssum[t - off] : 0u;
        __syncthreads();
        val += other;
        ssum[t] = val;
        __syncthreads();
    }
    unsigned c = val - lsum;                    // exclusive prefix of this thread's 8 bins
#pragma unroll
    for (int i = 0; i < 8; ++i) {
        if (k >= c && k < c + local[i]) {       // exactly one (t,i) matches
            unsigned bin = (unsigned)(t * 8 + i);
            if (PASS == 0)      { st->prefix = bin << 21; st->krem = k - c; }
            else if (PASS == 1) { st->prefix |= bin << 10; st->krem = k - c; }
            else                { st->threshold = fmaxf(__uint_as_float(st->prefix | bin), 0.7f); }
        }
        c += local[i];
    }
    __threadfence();
}

// ---------------- select: fast path (count>=K+1 -> thr=0.7, spec exact) or full
// cooperative 3-pass radix select + masked reduction (grid.sync between phases) ----
__global__ __launch_bounds__(256) void select_kernel(const float4* __restrict__ pred,
                                                     const float4* __restrict__ lossv,
                                                     const double* __restrict__ spec,
                                                     unsigned* __restrict__ hists,
                                                     SelState* st,
                                                     double* __restrict__ partials,
                                                     float* __restrict__ out) {
    cg::grid_group grid = cg::this_grid();
    __shared__ unsigned lh[NBINS];
    __shared__ double s1[256], s2[256];
    int t = threadIdx.x, bid = blockIdx.x;

    // Phase 0: every block redundantly sums the spec partials (16 KB, L2-resident).
    double a = 0.0, b = 0.0;
    for (int i = t; i < MAIN_BLOCKS; i += 256) { a += spec[2 * i]; b += spec[2 * i + 1]; }
    s1[t] = a; s2[t] = b;
    __syncthreads();
    for (int off = 128; off > 0; off >>= 1) {
        if (t < off) { s1[t] += s1[t + off]; s2[t] += s2[t + off]; }
        __syncthreads();
    }
    double SL = s1[0], SM = s2[0];
    if (SM >= (double)(K_RANK + 1)) {           // kth pred < 0.7 -> threshold = 0.7 exact
        if (bid == 0 && t == 0) out[0] = (float)(SL / fmax(SM, 1.0));
        return;                                 // no grid.sync ever executed on fast path
    }

    // ---- fallback: exact kth (>= 0.7) via 3-pass radix select ----
    for (int i = bid * 256 + t; i < 3 * NBINS; i += gridDim.x * 256) hists[i] = 0u;
    if (bid == 0 && t == 0) {
        st->prefix = 0u; st->krem = (unsigned)K_RANK; st->threshold = 0.7f;
        __threadfence();
    }
    grid.sync();

    hist_pass<0>(lh, pred, hists, 0u);
    grid.sync();
    if (bid == 0) scan_pass<0>(lh, hists, st);
    grid.sync();
    unsigned pfx = ((volatile SelState*)st)->prefix;

    hist_pass<1>(lh, pred, hists + NBINS, pfx);
    grid.sync();
    if (bid == 0) scan_pass<1>(lh, hists + NBINS, st);
    grid.sync();
    pfx = ((volatile SelState*)st)->prefix;

    hist_pass<2>(lh, pred, hists + 2 * NBINS, pfx);
    grid.sync();
    if (bid == 0) scan_pass<2>(lh, hists + 2 * NBINS, st);
    grid.sync();
    float thr = ((volatile SelState*)st)->threshold;

    // masked reduction at the exact threshold
    double sl = 0.0, sm = 0.0;
    for (int n = bid * 256 + t; n < N4; n += gridDim.x * 256) {
        float4 p  = pred[n];
        float4 lo = lossv[n];
        if (p.x < thr) { sl += (double)lo.x; sm += 1.0; }
        if (p.y < thr) { sl += (double)lo.y; sm += 1.0; }
        if (p.z < thr) { sl += (double)lo.z; sm += 1.0; }
        if (p.w < thr) { sl += (double)lo.w; sm += 1.0; }
    }
    __syncthreads();
    s1[t] = sl; s2[t] = sm;
    __syncthreads();
    for (int off = 128; off > 0; off >>= 1) {
        if (t < off) { s1[t] += s1[t + off]; s2[t] += s2[t + off]; }
        __syncthreads();
    }
    if (t == 0) { partials[2 * bid] = s1[0]; partials[2 * bid + 1] = s2[0]; }
    __threadfence();
    grid.sync();

    if (bid == 0) {
        double x = 0.0, y = 0.0;
        for (int i = t; i < (int)gridDim.x; i += 256) { x += partials[2 * i]; y += partials[2 * i + 1]; }
        __syncthreads();
        s1[t] = x; s2[t] = y;
        __syncthreads();
        for (int off = 128; off > 0; off >>= 1) {
            if (t < off) { s1[t] += s1[t + off]; s2[t] += s2[t + off]; }
            __syncthreads();
        }
        if (t == 0) out[0] = (float)(s1[0] / fmax(s2[0], 1.0));
    }
}

extern "C" void kernel_launch(void* const* d_in, const int* in_sizes, int n_in,
                              void* d_out, int out_size, void* d_ws, size_t ws_size,
                              hipStream_t stream) {
    const float4* logits = (const float4*)d_in[0];
    const float4* target = (const float4*)d_in[1];
    float* out = (float*)d_out;

    char* ws = (char*)d_ws;
    float4*   pred     = (float4*)ws;                                   // 8 MiB
    float4*   lossv    = (float4*)(ws + (size_t)N_ * 4);                // 8 MiB
    unsigned* hists    = (unsigned*)(ws + (size_t)N_ * 8);              // 24 KiB
    SelState* st       = (SelState*)(ws + (size_t)N_ * 8 + 3 * NBINS * 4);
    double*   spec     = (double*)(ws + (size_t)N_ * 8 + 3 * NBINS * 4 + 64);          // 16 KiB
    double*   partials = (double*)(ws + (size_t)N_ * 8 + 3 * NBINS * 4 + 64
                                      + (size_t)MAIN_BLOCKS * 2 * 8);                  // 8 KiB

    main_kernel<<<MAIN_BLOCKS, 256, 0, stream>>>(logits, target, pred, lossv, spec);

    void* args[] = { (void*)&pred, (void*)&lossv, (void*)&spec, (void*)&hists,
                     (void*)&st, (void*)&partials, (void*)&out };
    hipLaunchCooperativeKernel((const void*)select_kernel, dim3(SEL_BLOCKS), dim3(256),
                               args, 0, stream);
}

// Round 11
// 84.585 us; speedup vs baseline: 1.2311x; 1.2311x over previous
//
#include <hip/hip_runtime.h>
#include <hip/hip_cooperative_groups.h>

namespace cg = cooperative_groups;

#define B_ 8
#define C_ 19
#define H_ 512
#define W_ 512
#define HW_ (H_*W_)
#define N_ (B_*HW_)
#define HW4 (HW_/4)          /* 65536 float4 per channel-plane */
#define N4 (N_/4)            /* 524288 */
#define CH4 (C_*HW4)
#define K_RANK 100000
#define NBINS 2048
#define MAIN_BLOCKS (N4/512) /* 1024: 8 pixels (2 float4) per thread */
#define SEL_BLOCKS 512

struct SelState { unsigned prefix; unsigned krem; float threshold; };

typedef float f32x4 __attribute__((ext_vector_type(4)));

__device__ __forceinline__ float4 ntload(const float4* p) {
    f32x4 v = __builtin_nontemporal_load((const f32x4*)p);
    return make_float4(v.x, v.y, v.z, v.w);
}
__device__ __forceinline__ void ntstore(float4* p, float a, float b, float c, float d) {
    f32x4 v; v.x = a; v.y = b; v.z = c; v.w = d;
    __builtin_nontemporal_store(v, (f32x4*)p);
}

// ---------------- main: online-softmax CE, 8 pixels/thread (2 independent groups) ------
// nt LOADS: zero-reuse 318.8MB stream; cacheable path caps at ~2.7 TB/s (R1-4, R10) vs
// ~4.6 TB/s nt (R6-8) -- L2 allocation churn on a streaming read is pure overhead.
// nt STORES for pred/lossv: read at most once (fallback only); R10 showed cacheable
// stores amplify write traffic 3x (52MB vs 16.8MB program stores) via dirty-line churn.
__global__ __launch_bounds__(256, 4) void main_kernel(const float4* __restrict__ logits,
                                                      const float4* __restrict__ target,
                                                      float4* __restrict__ pred,
                                                      float4* __restrict__ lossv,
                                                      double* __restrict__ spec) {
    int t  = threadIdx.x;
    int n4 = blockIdx.x * 512 + t;                 // group A; group B = n4 + 256
    int b   = n4 >> 16;                            // block fully inside one batch b
    int hw4 = n4 & (HW4 - 1);
    size_t base = (size_t)b * (size_t)CH4 + (size_t)hw4;
    const float4* lp = logits + base;
    const float4* tp = target + base;

    float mA[4] = {-3.4e38f,-3.4e38f,-3.4e38f,-3.4e38f};
    float mB[4] = {-3.4e38f,-3.4e38f,-3.4e38f,-3.4e38f};
    float sA[4] = {0,0,0,0}, sB[4] = {0,0,0,0};
    float tsA[4] = {0,0,0,0}, tsB[4] = {0,0,0,0};
    float tlA[4] = {0,0,0,0}, tlB[4] = {0,0,0,0};

#pragma unroll
    for (int c = 0; c < C_; ++c) {
        float4 la = ntload(lp + (size_t)c * HW4);
        float4 lb = ntload(lp + (size_t)c * HW4 + 256);
        float4 ta = ntload(tp + (size_t)c * HW4);
        float4 tb = ntload(tp + (size_t)c * HW4 + 256);
        float lav[4] = { la.x, la.y, la.z, la.w };
        float lbv[4] = { lb.x, lb.y, lb.z, lb.w };
        float tav[4] = { ta.x, ta.y, ta.z, ta.w };
        float tbv[4] = { tb.x, tb.y, tb.z, tb.w };
#pragma unroll
        for (int j = 0; j < 4; ++j) {
            float na = fmaxf(mA[j], lav[j]);
            sA[j] = fmaf(sA[j], __expf(mA[j] - na), __expf(lav[j] - na)); mA[j] = na;
            tsA[j] += tav[j];
            tlA[j] = fmaf(tav[j], lav[j], tlA[j]);
            float nb = fmaxf(mB[j], lbv[j]);
            sB[j] = fmaf(sB[j], __expf(mB[j] - nb), __expf(lbv[j] - nb)); mB[j] = nb;
            tsB[j] += tbv[j];
            tlB[j] = fmaf(tbv[j], lbv[j], tlB[j]);
        }
    }

    float loA[4], prA[4], loB[4], prB[4];
#pragma unroll
    for (int j = 0; j < 4; ++j) {
        loA[j] = tsA[j] * (mA[j] + __logf(sA[j])) - tlA[j];
        prA[j] = __expf(tlA[j] - mA[j]) / sA[j];
        loB[j] = tsB[j] * (mB[j] + __logf(sB[j])) - tlB[j];
        prB[j] = __expf(tlB[j] - mB[j]) / sB[j];
    }
    ntstore(lossv + n4,       loA[0], loA[1], loA[2], loA[3]);
    ntstore(pred  + n4,       prA[0], prA[1], prA[2], prA[3]);
    ntstore(lossv + n4 + 256, loB[0], loB[1], loB[2], loB[3]);
    ntstore(pred  + n4 + 256, prB[0], prB[1], prB[2], prB[3]);

    // speculative thr == 0.7 masked partials (exact when kth < 0.7)
    double sl = 0.0, sm = 0.0;
#pragma unroll
    for (int j = 0; j < 4; ++j) {
        if (prA[j] < 0.7f) { sl += (double)loA[j]; sm += 1.0; }
        if (prB[j] < 0.7f) { sl += (double)loB[j]; sm += 1.0; }
    }
    __shared__ double sd1[256], sd2[256];
    sd1[t] = sl; sd2[t] = sm;
    __syncthreads();
    for (int off = 128; off > 0; off >>= 1) {
        if (t < off) { sd1[t] += sd1[t + off]; sd2[t] += sd2[t + off]; }
        __syncthreads();
    }
    if (t == 0) { spec[2 * blockIdx.x] = sd1[0]; spec[2 * blockIdx.x + 1] = sd2[0]; }
}

// ---------------- radix-select helpers (used only on the fallback path) ----------------
template <int PASS>
__device__ __forceinline__ void hist_pass(unsigned* lh, const float4* __restrict__ pred,
                                          unsigned* __restrict__ gh, unsigned prefix) {
    int t = threadIdx.x;
    for (int i = t; i < NBINS; i += 256) lh[i] = 0u;
    __syncthreads();
    int stride = gridDim.x * 256;
    for (int n = blockIdx.x * 256 + t; n < N4; n += stride) {
        float4 p = pred[n];
        unsigned u[4] = { __float_as_uint(p.x), __float_as_uint(p.y),
                          __float_as_uint(p.z), __float_as_uint(p.w) };
#pragma unroll
        for (int j = 0; j < 4; ++j) {
            unsigned v = u[j];
            if (PASS == 0)      atomicAdd(&lh[v >> 21], 1u);
            else if (PASS == 1) { if ((v & 0xFFE00000u) == prefix) atomicAdd(&lh[(v >> 10) & 0x7FFu], 1u); }
            else                { if ((v & 0xFFFFFC00u) == prefix) atomicAdd(&lh[v & 0x3FFu], 1u); }
        }
    }
    __syncthreads();
    for (int i = t; i < NBINS; i += 256) { unsigned v = lh[i]; if (v) atomicAdd(&gh[i], v); }
}

template <int PASS>
__device__ __forceinline__ void scan_pass(unsigned* ssum, const unsigned* __restrict__ gh,
                                          SelState* st) {
    int t = threadIdx.x;
    unsigned k = st->krem;
    unsigned local[8];
    unsigned lsum = 0;
#pragma unroll
    for (int i = 0; i < 8; ++i) { local[i] = gh[t * 8 + i]; lsum += local[i]; }
    ssum[t] = lsum;
    __syncthreads();
    unsigned val = lsum;
    for (int off = 1; off < 256; off <<= 1) {   // Hillis-Steele inclusive scan
        unsigned other = (t >= off) ? ssum[t - off] : 0u;
        __syncthreads();
        val += other;
        ssum[t] = val;
        __syncthreads();
    }
    unsigned c = val - lsum;                    // exclusive prefix of this thread's 8 bins
#pragma unroll
    for (int i = 0; i < 8; ++i) {
        if (k >= c && k < c + local[i]) {       // exactly one (t,i) matches
            unsigned bin = (unsigned)(t * 8 + i);
            if (PASS == 0)      { st->prefix = bin << 21; st->krem = k - c; }
            else if (PASS == 1) { st->prefix |= bin << 10; st->krem = k - c; }
            else                { st->threshold = fmaxf(__uint_as_float(st->prefix | bin), 0.7f); }
        }
        c += local[i];
    }
    __threadfence();
}

// ---------------- select: fast path (count>=K+1 -> thr=0.7, spec exact) or full
// cooperative 3-pass radix select + masked reduction (grid.sync between phases) ----
__global__ __launch_bounds__(256) void select_kernel(const float4* __restrict__ pred,
                                                     const float4* __restrict__ lossv,
                                                     const double* __restrict__ spec,
                                                     unsigned* __restrict__ hists,
                                                     SelState* st,
                                                     double* __restrict__ partials,
                                                     float* __restrict__ out) {
    cg::grid_group grid = cg::this_grid();
    __shared__ unsigned lh[NBINS];
    __shared__ double s1[256], s2[256];
    int t = threadIdx.x, bid = blockIdx.x;

    // Phase 0: every block redundantly sums the spec partials (16 KB, L2-resident).
    double a = 0.0, b = 0.0;
    for (int i = t; i < MAIN_BLOCKS; i += 256) { a += spec[2 * i]; b += spec[2 * i + 1]; }
    s1[t] = a; s2[t] = b;
    __syncthreads();
    for (int off = 128; off > 0; off >>= 1) {
        if (t < off) { s1[t] += s1[t + off]; s2[t] += s2[t + off]; }
        __syncthreads();
    }
    double SL = s1[0], SM = s2[0];
    if (SM >= (double)(K_RANK + 1)) {           // kth pred < 0.7 -> threshold = 0.7 exact
        if (bid == 0 && t == 0) out[0] = (float)(SL / fmax(SM, 1.0));
        return;                                 // no grid.sync ever executed on fast path
    }

    // ---- fallback: exact kth (>= 0.7) via 3-pass radix select ----
    for (int i = bid * 256 + t; i < 3 * NBINS; i += gridDim.x * 256) hists[i] = 0u;
    if (bid == 0 && t == 0) {
        st->prefix = 0u; st->krem = (unsigned)K_RANK; st->threshold = 0.7f;
        __threadfence();
    }
    grid.sync();

    hist_pass<0>(lh, pred, hists, 0u);
    grid.sync();
    if (bid == 0) scan_pass<0>(lh, hists, st);
    grid.sync();
    unsigned pfx = ((volatile SelState*)st)->prefix;

    hist_pass<1>(lh, pred, hists + NBINS, pfx);
    grid.sync();
    if (bid == 0) scan_pass<1>(lh, hists + NBINS, st);
    grid.sync();
    pfx = ((volatile SelState*)st)->prefix;

    hist_pass<2>(lh, pred, hists + 2 * NBINS, pfx);
    grid.sync();
    if (bid == 0) scan_pass<2>(lh, hists + 2 * NBINS, st);
    grid.sync();
    float thr = ((volatile SelState*)st)->threshold;

    // masked reduction at the exact threshold
    double sl = 0.0, sm = 0.0;
    for (int n = bid * 256 + t; n < N4; n += gridDim.x * 256) {
        float4 p  = pred[n];
        float4 lo = lossv[n];
        if (p.x < thr) { sl += (double)lo.x; sm += 1.0; }
        if (p.y < thr) { sl += (double)lo.y; sm += 1.0; }
        if (p.z < thr) { sl += (double)lo.z; sm += 1.0; }
        if (p.w < thr) { sl += (double)lo.w; sm += 1.0; }
    }
    __syncthreads();
    s1[t] = sl; s2[t] = sm;
    __syncthreads();
    for (int off = 128; off > 0; off >>= 1) {
        if (t < off) { s1[t] += s1[t + off]; s2[t] += s2[t + off]; }
        __syncthreads();
    }
    if (t == 0) { partials[2 * bid] = s1[0]; partials[2 * bid + 1] = s2[0]; }
    __threadfence();
    grid.sync();

    if (bid == 0) {
        double x = 0.0, y = 0.0;
        for (int i = t; i < (int)gridDim.x; i += 256) { x += partials[2 * i]; y += partials[2 * i + 1]; }
        __syncthreads();
        s1[t] = x; s2[t] = y;
        __syncthreads();
        for (int off = 128; off > 0; off >>= 1) {
            if (t < off) { s1[t] += s1[t + off]; s2[t] += s2[t + off]; }
            __syncthreads();
        }
        if (t == 0) out[0] = (float)(s1[0] / fmax(s2[0], 1.0));
    }
}

extern "C" void kernel_launch(void* const* d_in, const int* in_sizes, int n_in,
                              void* d_out, int out_size, void* d_ws, size_t ws_size,
                              hipStream_t stream) {
    const float4* logits = (const float4*)d_in[0];
    const float4* target = (const float4*)d_in[1];
    float* out = (float*)d_out;

    char* ws = (char*)d_ws;
    float4*   pred     = (float4*)ws;                                   // 8 MiB
    float4*   lossv    = (float4*)(ws + (size_t)N_ * 4);                // 8 MiB
    unsigned* hists    = (unsigned*)(ws + (size_t)N_ * 8);              // 24 KiB
    SelState* st       = (SelState*)(ws + (size_t)N_ * 8 + 3 * NBINS * 4);
    double*   spec     = (double*)(ws + (size_t)N_ * 8 + 3 * NBINS * 4 + 64);          // 16 KiB
    double*   partials = (double*)(ws + (size_t)N_ * 8 + 3 * NBINS * 4 + 64
                                      + (size_t)MAIN_BLOCKS * 2 * 8);                  // 8 KiB

    main_kernel<<<MAIN_BLOCKS, 256, 0, stream>>>(logits, target, pred, lossv, spec);

    void* args[] = { (void*)&pred, (void*)&lossv, (void*)&spec, (void*)&hists,
                     (void*)&st, (void*)&partials, (void*)&out };
    hipLaunchCooperativeKernel((const void*)select_kernel, dim3(SEL_BLOCKS), dim3(256),
                               args, 0, stream);
}

// Round 12
// 75.273 us; speedup vs baseline: 1.3834x; 1.1237x over previous
//
#include <hip/hip_runtime.h>
#include <hip/hip_cooperative_groups.h>

namespace cg = cooperative_groups;

#define B_ 8
#define C_ 19
#define H_ 512
#define W_ 512
#define HW_ (H_*W_)
#define N_ (B_*HW_)
#define HW4 (HW_/4)          /* 65536 float4 per channel-plane */
#define N4 (N_/4)            /* 524288 */
#define CH4 (C_*HW4)
#define K_RANK 100000
#define NBINS 2048
#define MAIN_BLOCKS (N4/512) /* 1024: 8 pixels (2 float4) per thread */
#define SEL_BLOCKS 512

struct SelState { unsigned prefix; unsigned krem; float threshold; };

typedef float f32x4 __attribute__((ext_vector_type(4)));

__device__ __forceinline__ float4 ntload(const float4* p) {
    f32x4 v = __builtin_nontemporal_load((const f32x4*)p);
    return make_float4(v.x, v.y, v.z, v.w);
}

// Shared per-float4 online-softmax CE: returns loss/pred for 4 pixels at flat index n4.
__device__ __forceinline__ void ce4(const float4* __restrict__ logits,
                                    const float4* __restrict__ target,
                                    int n4, float4& lo, float4& pr) {
    int b   = n4 >> 16;
    int hw4 = n4 & (HW4 - 1);
    size_t base = (size_t)b * (size_t)CH4 + (size_t)hw4;
    const float4* lp = logits + base;
    const float4* tp = target + base;
    float m[4] = {-3.4e38f,-3.4e38f,-3.4e38f,-3.4e38f};
    float s[4] = {0,0,0,0}, ts[4] = {0,0,0,0}, tl[4] = {0,0,0,0};
#pragma unroll
    for (int c = 0; c < C_; ++c) {
        float4 l4 = ntload(lp + (size_t)c * HW4);
        float4 t4 = ntload(tp + (size_t)c * HW4);
        float lv[4] = { l4.x, l4.y, l4.z, l4.w };
        float tv[4] = { t4.x, t4.y, t4.z, t4.w };
#pragma unroll
        for (int j = 0; j < 4; ++j) {
            float n = fmaxf(m[j], lv[j]);
            s[j] = fmaf(s[j], __expf(m[j] - n), __expf(lv[j] - n)); m[j] = n;
            ts[j] += tv[j];
            tl[j] = fmaf(tv[j], lv[j], tl[j]);
        }
    }
    float lov[4], prv[4];
#pragma unroll
    for (int j = 0; j < 4; ++j) {
        lov[j] = ts[j] * (m[j] + __logf(s[j])) - tl[j];
        prv[j] = __expf(tl[j] - m[j]) / s[j];
    }
    lo = make_float4(lov[0], lov[1], lov[2], lov[3]);
    pr = make_float4(prv[0], prv[1], prv[2], prv[3]);
}

// ---------------- main: online-softmax CE, 8 pixels/thread, NO pred/loss stores --------
// The timed (fast) path only needs the spec partials { sum(loss*[pred<0.7]), count }.
// pred/lossv materialization is deferred to the fallback branch of select_kernel
// (recomputed there with the identical formula; fallback never runs when kth pred < 0.7).
// nt loads: zero-reuse 318.8MB stream; cacheable caps at ~2.7 TB/s vs ~4.6 TB/s nt.
__global__ __launch_bounds__(256, 4) void main_kernel(const float4* __restrict__ logits,
                                                      const float4* __restrict__ target,
                                                      double* __restrict__ spec) {
    int t  = threadIdx.x;
    int n4 = blockIdx.x * 512 + t;                 // group A; group B = n4 + 256
    float4 loA, prA, loB, prB;
    ce4(logits, target, n4,       loA, prA);
    ce4(logits, target, n4 + 256, loB, prB);

    double sl = 0.0, sm = 0.0;
    if (prA.x < 0.7f) { sl += (double)loA.x; sm += 1.0; }
    if (prA.y < 0.7f) { sl += (double)loA.y; sm += 1.0; }
    if (prA.z < 0.7f) { sl += (double)loA.z; sm += 1.0; }
    if (prA.w < 0.7f) { sl += (double)loA.w; sm += 1.0; }
    if (prB.x < 0.7f) { sl += (double)loB.x; sm += 1.0; }
    if (prB.y < 0.7f) { sl += (double)loB.y; sm += 1.0; }
    if (prB.z < 0.7f) { sl += (double)loB.z; sm += 1.0; }
    if (prB.w < 0.7f) { sl += (double)loB.w; sm += 1.0; }

    __shared__ double sd1[256], sd2[256];
    sd1[t] = sl; sd2[t] = sm;
    __syncthreads();
    for (int off = 128; off > 0; off >>= 1) {
        if (t < off) { sd1[t] += sd1[t + off]; sd2[t] += sd2[t + off]; }
        __syncthreads();
    }
    if (t == 0) { spec[2 * blockIdx.x] = sd1[0]; spec[2 * blockIdx.x + 1] = sd2[0]; }
}

// ---------------- radix-select helpers (fallback path only) ----------------
template <int PASS>
__device__ __forceinline__ void hist_pass(unsigned* lh, const float4* __restrict__ pred,
                                          unsigned* __restrict__ gh, unsigned prefix) {
    int t = threadIdx.x;
    for (int i = t; i < NBINS; i += 256) lh[i] = 0u;
    __syncthreads();
    int stride = gridDim.x * 256;
    for (int n = blockIdx.x * 256 + t; n < N4; n += stride) {
        float4 p = pred[n];
        unsigned u[4] = { __float_as_uint(p.x), __float_as_uint(p.y),
                          __float_as_uint(p.z), __float_as_uint(p.w) };
#pragma unroll
        for (int j = 0; j < 4; ++j) {
            unsigned v = u[j];
            if (PASS == 0)      atomicAdd(&lh[v >> 21], 1u);
            else if (PASS == 1) { if ((v & 0xFFE00000u) == prefix) atomicAdd(&lh[(v >> 10) & 0x7FFu], 1u); }
            else                { if ((v & 0xFFFFFC00u) == prefix) atomicAdd(&lh[v & 0x3FFu], 1u); }
        }
    }
    __syncthreads();
    for (int i = t; i < NBINS; i += 256) { unsigned v = lh[i]; if (v) atomicAdd(&gh[i], v); }
}

template <int PASS>
__device__ __forceinline__ void scan_pass(unsigned* ssum, const unsigned* __restrict__ gh,
                                          SelState* st) {
    int t = threadIdx.x;
    unsigned k = st->krem;
    unsigned local[8];
    unsigned lsum = 0;
#pragma unroll
    for (int i = 0; i < 8; ++i) { local[i] = gh[t * 8 + i]; lsum += local[i]; }
    ssum[t] = lsum;
    __syncthreads();
    unsigned val = lsum;
    for (int off = 1; off < 256; off <<= 1) {   // Hillis-Steele inclusive scan
        unsigned other = (t >= off) ? ssum[t - off] : 0u;
        __syncthreads();
        val += other;
        ssum[t] = val;
        __syncthreads();
    }
    unsigned c = val - lsum;                    // exclusive prefix of this thread's 8 bins
#pragma unroll
    for (int i = 0; i < 8; ++i) {
        if (k >= c && k < c + local[i]) {       // exactly one (t,i) matches
            unsigned bin = (unsigned)(t * 8 + i);
            if (PASS == 0)      { st->prefix = bin << 21; st->krem = k - c; }
            else if (PASS == 1) { st->prefix |= bin << 10; st->krem = k - c; }
            else                { st->threshold = fmaxf(__uint_as_float(st->prefix | bin), 0.7f); }
        }
        c += local[i];
    }
    __threadfence();
}

// ---------------- select: fast path (count>=K+1 -> thr=0.7, spec exact) or full
// fallback: materialize pred/lossv (recompute), 3-pass radix select, masked reduction ----
__global__ __launch_bounds__(256) void select_kernel(const float4* __restrict__ logits,
                                                     const float4* __restrict__ target,
                                                     float4* __restrict__ pred,
                                                     float4* __restrict__ lossv,
                                                     const double* __restrict__ spec,
                                                     unsigned* __restrict__ hists,
                                                     SelState* st,
                                                     double* __restrict__ partials,
                                                     float* __restrict__ out) {
    cg::grid_group grid = cg::this_grid();
    __shared__ unsigned lh[NBINS];
    __shared__ double s1[256], s2[256];
    int t = threadIdx.x, bid = blockIdx.x;

    // Phase 0: every block redundantly sums the spec partials (16 KB, L2-resident).
    double a = 0.0, b = 0.0;
    for (int i = t; i < MAIN_BLOCKS; i += 256) { a += spec[2 * i]; b += spec[2 * i + 1]; }
    s1[t] = a; s2[t] = b;
    __syncthreads();
    for (int off = 128; off > 0; off >>= 1) {
        if (t < off) { s1[t] += s1[t + off]; s2[t] += s2[t + off]; }
        __syncthreads();
    }
    double SL = s1[0], SM = s2[0];
    if (SM >= (double)(K_RANK + 1)) {           // kth pred < 0.7 -> threshold = 0.7 exact
        if (bid == 0 && t == 0) out[0] = (float)(SL / fmax(SM, 1.0));
        return;                                 // no grid.sync ever executed on fast path
    }

    // ---- fallback: materialize pred/lossv (identical formula, deterministic) ----
    for (int n = bid * 256 + t; n < N4; n += gridDim.x * 256) {
        float4 lo, pr;
        ce4(logits, target, n, lo, pr);
        lossv[n] = lo;
        pred[n]  = pr;
    }
    for (int i = bid * 256 + t; i < 3 * NBINS; i += gridDim.x * 256) hists[i] = 0u;
    if (bid == 0 && t == 0) {
        st->prefix = 0u; st->krem = (unsigned)K_RANK; st->threshold = 0.7f;
    }
    __threadfence();
    grid.sync();

    hist_pass<0>(lh, pred, hists, 0u);
    grid.sync();
    if (bid == 0) scan_pass<0>(lh, hists, st);
    grid.sync();
    unsigned pfx = ((volatile SelState*)st)->prefix;

    hist_pass<1>(lh, pred, hists + NBINS, pfx);
    grid.sync();
    if (bid == 0) scan_pass<1>(lh, hists + NBINS, st);
    grid.sync();
    pfx = ((volatile SelState*)st)->prefix;

    hist_pass<2>(lh, pred, hists + 2 * NBINS, pfx);
    grid.sync();
    if (bid == 0) scan_pass<2>(lh, hists + 2 * NBINS, st);
    grid.sync();
    float thr = ((volatile SelState*)st)->threshold;

    // masked reduction at the exact threshold
    double sl = 0.0, sm = 0.0;
    for (int n = bid * 256 + t; n < N4; n += gridDim.x * 256) {
        float4 p  = pred[n];
        float4 lo = lossv[n];
        if (p.x < thr) { sl += (double)lo.x; sm += 1.0; }
        if (p.y < thr) { sl += (double)lo.y; sm += 1.0; }
        if (p.z < thr) { sl += (double)lo.z; sm += 1.0; }
        if (p.w < thr) { sl += (double)lo.w; sm += 1.0; }
    }
    __syncthreads();
    s1[t] = sl; s2[t] = sm;
    __syncthreads();
    for (int off = 128; off > 0; off >>= 1) {
        if (t < off) { s1[t] += s1[t + off]; s2[t] += s2[t + off]; }
        __syncthreads();
    }
    if (t == 0) { partials[2 * bid] = s1[0]; partials[2 * bid + 1] = s2[0]; }
    __threadfence();
    grid.sync();

    if (bid == 0) {
        double x = 0.0, y = 0.0;
        for (int i = t; i < (int)gridDim.x; i += 256) { x += partials[2 * i]; y += partials[2 * i + 1]; }
        __syncthreads();
        s1[t] = x; s2[t] = y;
        __syncthreads();
        for (int off = 128; off > 0; off >>= 1) {
            if (t < off) { s1[t] += s1[t + off]; s2[t] += s2[t + off]; }
            __syncthreads();
        }
        if (t == 0) out[0] = (float)(s1[0] / fmax(s2[0], 1.0));
    }
}

extern "C" void kernel_launch(void* const* d_in, const int* in_sizes, int n_in,
                              void* d_out, int out_size, void* d_ws, size_t ws_size,
                              hipStream_t stream) {
    const float4* logits = (const float4*)d_in[0];
    const float4* target = (const float4*)d_in[1];
    float* out = (float*)d_out;

    char* ws = (char*)d_ws;
    float4*   pred     = (float4*)ws;                                   // 8 MiB (fallback only)
    float4*   lossv    = (float4*)(ws + (size_t)N_ * 4);                // 8 MiB (fallback only)
    unsigned* hists    = (unsigned*)(ws + (size_t)N_ * 8);              // 24 KiB
    SelState* st       = (SelState*)(ws + (size_t)N_ * 8 + 3 * NBINS * 4);
    double*   spec     = (double*)(ws + (size_t)N_ * 8 + 3 * NBINS * 4 + 64);          // 16 KiB
    double*   partials = (double*)(ws + (size_t)N_ * 8 + 3 * NBINS * 4 + 64
                                      + (size_t)MAIN_BLOCKS * 2 * 8);                  // 8 KiB

    main_kernel<<<MAIN_BLOCKS, 256, 0, stream>>>(logits, target, spec);

    void* args[] = { (void*)&logits, (void*)&target, (void*)&pred, (void*)&lossv,
                     (void*)&spec, (void*)&hists, (void*)&st, (void*)&partials, (void*)&out };
    hipLaunchCooperativeKernel((const void*)select_kernel, dim3(SEL_BLOCKS), dim3(256),
                               args, 0, stream);
}